// Round 3
// baseline (1112.860 us; speedup 1.0000x reference)
//
#include <hip/hip_runtime.h>
#include <hip/hip_cooperative_groups.h>

namespace cg = cooperative_groups;

#define B 4
#define N 2048
#define MAXIT 11       // body runs for it = 0..10
#define TOL 1e-4f
#define CC 512         // candidates per nn chunk
#define QC 256         // queries per nn chunk
#define NBLK 128       // 4 cand-chunks x 4 batches x 8 query-chunks

// ---------------- workspace layout ----------------
// [0,       98304)   float temp_pc[B][N][3]
// [98304,  163840)   unsigned long long nn0[B][N]   (parity slot 0)
// [163840, 229376)   unsigned long long nn1[B][N]   (parity slot 1)
// [229376, 229380)   float prev_err
// [229380, 229384)   int done

// ---------------- 3x3 helpers (double, thread-serial) ----------------
__device__ double det3(const double* M) {
    return M[0]*(M[4]*M[8]-M[5]*M[7])
         - M[1]*(M[3]*M[8]-M[5]*M[6])
         + M[2]*(M[3]*M[7]-M[4]*M[6]);
}

// SVD of 3x3 A (row-major): A = U * diag(sig) * V^T, sig sorted descending.
__device__ void svd3x3(const double* A, double* U, double* V, double* sig) {
    double S[9];
    for (int i = 0; i < 3; ++i)
        for (int j = 0; j < 3; ++j) {
            double s = 0.0;
            for (int k = 0; k < 3; ++k) s += A[k*3+i] * A[k*3+j];
            S[i*3+j] = s;
        }
    double Vm[9] = {1,0,0, 0,1,0, 0,0,1};
    for (int sweep = 0; sweep < 30; ++sweep) {
        double off = fabs(S[1]) + fabs(S[2]) + fabs(S[5]);
        double base = fabs(S[0]) + fabs(S[4]) + fabs(S[8]);
        if (off <= 1e-15 * base) break;
        for (int pi = 0; pi < 3; ++pi) {
            const int p = (pi == 2) ? 1 : 0;
            const int q = (pi == 0) ? 1 : 2;
            double apq = S[p*3+q];
            if (apq == 0.0) continue;
            double app = S[p*3+p], aqq = S[q*3+q];
            double tau = (aqq - app) / (2.0 * apq);
            double tt  = ((tau >= 0.0) ? 1.0 : -1.0) / (fabs(tau) + sqrt(1.0 + tau*tau));
            double c = 1.0 / sqrt(1.0 + tt*tt);
            double s = tt * c;
            for (int k = 0; k < 3; ++k) {
                double skp = S[k*3+p], skq = S[k*3+q];
                S[k*3+p] = c*skp - s*skq;
                S[k*3+q] = s*skp + c*skq;
            }
            for (int k = 0; k < 3; ++k) {
                double spk = S[p*3+k], sqk = S[q*3+k];
                S[p*3+k] = c*spk - s*sqk;
                S[q*3+k] = s*spk + c*sqk;
            }
            for (int k = 0; k < 3; ++k) {
                double vkp = Vm[k*3+p], vkq = Vm[k*3+q];
                Vm[k*3+p] = c*vkp - s*vkq;
                Vm[k*3+q] = s*vkp + c*vkq;
            }
        }
    }
    double lam[3] = {S[0], S[4], S[8]};
    int ord[3] = {0, 1, 2};
    for (int i = 0; i < 2; ++i)
        for (int j = i+1; j < 3; ++j)
            if (lam[ord[j]] > lam[ord[i]]) { int tmp = ord[i]; ord[i] = ord[j]; ord[j] = tmp; }
    for (int i = 0; i < 3; ++i) {
        int o = ord[i];
        double l = lam[o] > 0.0 ? lam[o] : 0.0;
        sig[i] = sqrt(l);
        for (int k = 0; k < 3; ++k) V[k*3+i] = Vm[k*3+o];
    }
    for (int i = 0; i < 3; ++i) {
        double u0 = 0, u1 = 0, u2 = 0;
        for (int k = 0; k < 3; ++k) {
            u0 += A[0*3+k] * V[k*3+i];
            u1 += A[1*3+k] * V[k*3+i];
            u2 += A[2*3+k] * V[k*3+i];
        }
        double nrm = sqrt(u0*u0 + u1*u1 + u2*u2);
        if (nrm > 1e-300) { u0 /= nrm; u1 /= nrm; u2 /= nrm; }
        else {
            double ax = U[0], ay = U[3], az = U[6];
            double bx = U[1], by = U[4], bz = U[7];
            u0 = ay*bz - az*by; u1 = az*bx - ax*bz; u2 = ax*by - ay*bx;
        }
        U[0*3+i] = u0; U[1*3+i] = u1; U[2*3+i] = u2;
    }
}

// u,s,vT = svd(H); v=vT^T; d=det(v@u^T); v[2,2]*=d; R = v' @ u^T;
// t[j] = p2c[j] - sum_k p1c[k]*R[k][j]
__device__ void compute_Rt(const double* H, const double* p1c, const double* p2c,
                           float* Rout, float* tout) {
    double U[9], V[9], sig[3];
    svd3x3(H, U, V, sig);
    double d = (det3(U) * det3(V) < 0.0) ? -1.0 : 1.0;
    V[2*3+2] *= d;
    double R[9];
    for (int i = 0; i < 3; ++i)
        for (int j = 0; j < 3; ++j) {
            double s = 0.0;
            for (int k = 0; k < 3; ++k) s += V[i*3+k] * U[j*3+k];
            R[i*3+j] = s;
        }
    for (int j = 0; j < 3; ++j) {
        double s = 0.0;
        for (int k = 0; k < 3; ++k) s += p1c[k] * R[k*3+j];
        tout[j] = (float)(p2c[j] - s);
    }
    for (int k = 0; k < 9; ++k) Rout[k] = (float)R[k];
}

__device__ inline float wred(float v) {
    v += __shfl_down(v, 32);
    v += __shfl_down(v, 16);
    v += __shfl_down(v, 8);
    v += __shfl_down(v, 4);
    v += __shfl_down(v, 2);
    v += __shfl_down(v, 1);
    return v;   // valid on lane 0 of each wave
}

// Per-batch rigid-transform estimation + application, shared by loop body and
// final step. matched[i] = src2[3*(b*N+gather(i))] with gather from idx array
// (or identity for the final step).
__device__ void batch_transform(const float* __restrict__ src1,  // [b*N..] "q1" cloud
                                const float* __restrict__ src2,  // [b*N..] "q2" cloud
                                const unsigned long long* __restrict__ nn_idx, // batch-3 row or null
                                int b, int t,
                                float lred[4][9], float* sc1, float* sc2,
                                float* sR, float* sT) {
    const int wave = t >> 6, lane = t & 63;
    float v6[6] = {0,0,0,0,0,0};
    for (int i = t; i < N; i += 256) {
        const float* tp = &src1[(b*N + i)*3];
        v6[0] += tp[0]; v6[1] += tp[1]; v6[2] += tp[2];
        const int mi = nn_idx ? (int)(unsigned int)(nn_idx[i] & 0xffffffffULL) : i;
        const float* mp = &src2[(b*N + mi)*3];
        v6[3] += mp[0]; v6[4] += mp[1]; v6[5] += mp[2];
    }
    #pragma unroll
    for (int k = 0; k < 6; ++k) v6[k] = wred(v6[k]);
    if (lane == 0) {
        #pragma unroll
        for (int k = 0; k < 6; ++k) lred[wave][k] = v6[k];
    }
    __syncthreads();
    if (t == 0) {
        #pragma unroll
        for (int k = 0; k < 3; ++k) {
            sc1[k] = (lred[0][k]  +lred[1][k]  +lred[2][k]  +lred[3][k])   / (float)N;
            sc2[k] = (lred[0][3+k]+lred[1][3+k]+lred[2][3+k]+lred[3][3+k]) / (float)N;
        }
    }
    __syncthreads();
    const float c1x = sc1[0], c1y = sc1[1], c1z = sc1[2];
    const float c2x = sc2[0], c2y = sc2[1], c2z = sc2[2];

    float h[9];
    #pragma unroll
    for (int k = 0; k < 9; ++k) h[k] = 0.f;
    for (int i = t; i < N; i += 256) {
        const float* tp = &src1[(b*N + i)*3];
        const int mi = nn_idx ? (int)(unsigned int)(nn_idx[i] & 0xffffffffULL) : i;
        const float* mp = &src2[(b*N + mi)*3];
        const float bx = tp[0]-c1x, by = tp[1]-c1y, bz = tp[2]-c1z; // q1
        const float ax = mp[0]-c2x, ay = mp[1]-c2y, az = mp[2]-c2z; // q2
        h[0] += ax*bx; h[1] += ax*by; h[2] += ax*bz;
        h[3] += ay*bx; h[4] += ay*by; h[5] += ay*bz;
        h[6] += az*bx; h[7] += az*by; h[8] += az*bz;
    }
    #pragma unroll
    for (int k = 0; k < 9; ++k) h[k] = wred(h[k]);
    if (lane == 0) {
        #pragma unroll
        for (int k = 0; k < 9; ++k) lred[wave][k] = h[k];
    }
    __syncthreads();
    if (t == 0) {
        double H[9], c1d[3], c2d[3];
        for (int k = 0; k < 9; ++k)
            H[k] = (double)(lred[0][k]+lred[1][k]+lred[2][k]+lred[3][k]);
        c1d[0] = c1x; c1d[1] = c1y; c1d[2] = c1z;
        c2d[0] = c2x; c2d[1] = c2y; c2d[2] = c2z;
        compute_Rt(H, c1d, c2d, sR, sT);
    }
    __syncthreads();
}

// ---------------- the single cooperative kernel ----------------
__global__ void __launch_bounds__(256) k_icp(const float* __restrict__ p1,
                                             const float* __restrict__ p2,
                                             float* __restrict__ out,
                                             float* __restrict__ temp,
                                             unsigned long long* __restrict__ nn0,
                                             unsigned long long* __restrict__ nn1,
                                             float* __restrict__ scal,
                                             int* __restrict__ done_flag) {
    cg::grid_group grid = cg::this_grid();
    const int t   = threadIdx.x;
    const int blk = blockIdx.x;

    __shared__ float sc[CC * 3];
    __shared__ float lred[4][9];
    __shared__ float sc1[3], sc2[3], sR[9], sT[3];
    __shared__ float lds4[4];
    __shared__ int sdone;

    // ---- init: temp = p1, nn0 = empty, scalars = 0 ----
    for (int i = blk*256 + t; i < B*N*3; i += NBLK*256) temp[i] = p1[i];
    for (int i = blk*256 + t; i < B*N;   i += NBLK*256) nn0[i] = ~0ULL;
    if (blk == 0 && t == 0) {
        scal[0] = 0.0f;
        __hip_atomic_store(done_flag, 0, __ATOMIC_RELAXED, __HIP_MEMORY_SCOPE_AGENT);
    }
    __threadfence();
    grid.sync();
    __threadfence();

    for (int it = 0; it < MAXIT; ++it) {
        if (t == 0)
            sdone = __hip_atomic_load(done_flag, __ATOMIC_RELAXED, __HIP_MEMORY_SCOPE_AGENT);
        __syncthreads();
        if (sdone) break;

        unsigned long long* nn_cur  = (it & 1) ? nn1 : nn0;
        unsigned long long* nn_next = (it & 1) ? nn0 : nn1;

        // ---- NN phase: all 128 blocks ----
        {
            const int c  = blk & 3;
            const int b  = (blk >> 2) & 3;
            const int qc = blk >> 4;
            const int cb = c * CC, qb = qc * QC;
            for (int i = t; i < CC*3; i += 256)
                sc[i] = temp[(b*N + cb)*3 + i];
            __syncthreads();
            const int q = qb + t;
            const float px = p2[(b*N+q)*3+0];
            const float py = p2[(b*N+q)*3+1];
            const float pz = p2[(b*N+q)*3+2];
            float bestd = __uint_as_float(0x7f7fffffu);  // FLT_MAX
            int   besti = 0;
            for (int j = 0; j < CC; ++j) {
                float dx = px - sc[j*3+0];
                float dy = py - sc[j*3+1];
                float dz = pz - sc[j*3+2];
                float d2 = dx*dx + dy*dy + dz*dz;
                if (d2 < bestd) { bestd = d2; besti = cb + j; }
            }
            unsigned long long pack =
                ((unsigned long long)__float_as_uint(bestd) << 32) | (unsigned int)besti;
            atomicMin(&nn_cur[b*N + q], pack);
            __syncthreads();
        }
        __threadfence();
        grid.sync();
        __threadfence();

        // ---- reduce phase: blocks 0..3 per-batch, block 4 mean-err ----
        if (blk == 4) {
            float s = 0.f;
            for (int i = t; i < B*N; i += 256) {
                unsigned int dbits = (unsigned int)(nn_cur[i] >> 32);
                s += sqrtf(__uint_as_float(dbits));
                nn_next[i] = ~0ULL;
            }
            s = wred(s);
            if ((t & 63) == 0) lds4[t >> 6] = s;
            __syncthreads();
            if (t == 0) {
                float tot = lds4[0] + lds4[1] + lds4[2] + lds4[3];
                float meanerr = tot / (float)(B*N);
                float prev = scal[0];
                scal[0] = meanerr;
                __hip_atomic_store(done_flag,
                                   (fabsf(prev - meanerr) < TOL) ? 1 : 0,
                                   __ATOMIC_RELAXED, __HIP_MEMORY_SCOPE_AGENT);
            }
        } else if (blk < 4) {
            const int b = blk;
            batch_transform(temp, p2, &nn_cur[3*N], b, t, lred, sc1, sc2, sR, sT);
            // temp[b] = temp[b] @ R + t
            for (int i = t; i < N; i += 256) {
                float* tp = &temp[(b*N + i)*3];
                const float x = tp[0], y = tp[1], z = tp[2];
                tp[0] = x*sR[0] + y*sR[3] + z*sR[6] + sT[0];
                tp[1] = x*sR[1] + y*sR[4] + z*sR[7] + sT[1];
                tp[2] = x*sR[2] + y*sR[5] + z*sR[8] + sT[2];
            }
        }
        __threadfence();
        grid.sync();
        __threadfence();
    }

    // ---- final: T = get_transform(p1, temp) ----
    if (blk < 4) {
        const int b = blk;
        batch_transform(p1, temp, nullptr, b, t, lred, sc1, sc2, sR, sT);
        if (t == 0) {
            for (int i = 0; i < 3; ++i) {
                out[b*12 + i*4 + 0] = sR[i*3+0];
                out[b*12 + i*4 + 1] = sR[i*3+1];
                out[b*12 + i*4 + 2] = sR[i*3+2];
                out[b*12 + i*4 + 3] = sT[i];
            }
        }
    }
}

extern "C" void kernel_launch(void* const* d_in, const int* in_sizes, int n_in,
                              void* d_out, int out_size, void* d_ws, size_t ws_size,
                              hipStream_t stream) {
    const float* p1 = (const float*)d_in[0];
    const float* p2 = (const float*)d_in[1];
    float* out  = (float*)d_out;
    float* temp = (float*)d_ws;
    unsigned long long* nn0 = (unsigned long long*)((char*)d_ws + 98304);
    unsigned long long* nn1 = (unsigned long long*)((char*)d_ws + 163840);
    float* scal = (float*)((char*)d_ws + 229376);
    int*   done = (int*)((char*)d_ws + 229380);

    void* args[] = { (void*)&p1, (void*)&p2, (void*)&out, (void*)&temp,
                     (void*)&nn0, (void*)&nn1, (void*)&scal, (void*)&done };
    hipLaunchCooperativeKernel((const void*)k_icp, dim3(NBLK), dim3(256),
                               args, 0, stream);
}

// Round 4
// 461.815 us; speedup vs baseline: 2.4098x; 2.4098x over previous
//
#include <hip/hip_runtime.h>

#define B 4
#define N 2048
#define MAXIT 11       // body runs for it = 0..10
#define TOL 1e-4f
#define CC 128         // candidates per nn chunk
#define NQ 4           // queries per thread (register-blocked)
#define NBLK 128       // 16 cand-chunks x 2 query-chunks x 4 batches

// ---------------- workspace layout ----------------
// [0,       98304)   float temp_pc[B][N][3]        (coh access only)
// [98304,  163840)   unsigned long long nn0[B][N]  (coh)
// [163840, 229376)   unsigned long long nn1[B][N]  (coh)
// [229376, 229380)   unsigned barrier_cnt          (memset 0 pre-launch)
// [229632, 229636)   int done                      (memset 0 pre-launch)

// -------- coherent (L2-bypassing, MALL-backed) access helpers --------
__device__ __forceinline__ float cohldf(const float* p) {
    return __hip_atomic_load(p, __ATOMIC_RELAXED, __HIP_MEMORY_SCOPE_AGENT);
}
__device__ __forceinline__ void cohstf(float* p, float v) {
    __hip_atomic_store(p, v, __ATOMIC_RELAXED, __HIP_MEMORY_SCOPE_AGENT);
}
__device__ __forceinline__ unsigned long long cohld64(const unsigned long long* p) {
    return __hip_atomic_load(p, __ATOMIC_RELAXED, __HIP_MEMORY_SCOPE_AGENT);
}
__device__ __forceinline__ void cohst64(unsigned long long* p, unsigned long long v) {
    __hip_atomic_store(p, v, __ATOMIC_RELAXED, __HIP_MEMORY_SCOPE_AGENT);
}
template<bool COH>
__device__ __forceinline__ float ldf(const float* p) {
    return COH ? cohldf(p) : *p;
}

// -------- lean grid barrier: monotone counter, no cache maintenance --------
// All cross-block data is sc1 (coherent-at-MALL), so the only requirements are
// (1) our stores/atomics drained before arrive (s_waitcnt 0) and (2) compiler
// ordering (signal fences). No buffer_wbl2 / threadfence anywhere.
__device__ __forceinline__ void gridbar(unsigned* cnt, unsigned bar_idx) {
    __syncthreads();
    if (threadIdx.x == 0) {
        __atomic_signal_fence(__ATOMIC_SEQ_CST);
        __builtin_amdgcn_s_waitcnt(0);   // drain this wave's coh stores/atomics
        __hip_atomic_fetch_add(cnt, 1u, __ATOMIC_RELAXED, __HIP_MEMORY_SCOPE_AGENT);
        const unsigned target = bar_idx * (unsigned)NBLK;
        long long guard = 0;
        while (__hip_atomic_load(cnt, __ATOMIC_RELAXED, __HIP_MEMORY_SCOPE_AGENT) < target) {
            __builtin_amdgcn_s_sleep(2);
            if (++guard > (1LL << 22)) break;   // failsafe: wrong > hung
        }
        __atomic_signal_fence(__ATOMIC_SEQ_CST);
    }
    __syncthreads();
}

// ---------------- 3x3 helpers (float, thread-serial) ----------------
__device__ float det3f(const float* M) {
    return M[0]*(M[4]*M[8]-M[5]*M[7])
         - M[1]*(M[3]*M[8]-M[5]*M[6])
         + M[2]*(M[3]*M[7]-M[4]*M[6]);
}

// SVD of 3x3 A (row-major): A = U * diag(sig) * V^T, sig sorted descending.
__device__ void svd3x3f(const float* A, float* U, float* V, float* sig) {
    float S[9];
    for (int i = 0; i < 3; ++i)
        for (int j = 0; j < 3; ++j) {
            float s = 0.f;
            for (int k = 0; k < 3; ++k) s += A[k*3+i] * A[k*3+j];
            S[i*3+j] = s;
        }
    float Vm[9] = {1,0,0, 0,1,0, 0,0,1};
    for (int sweep = 0; sweep < 20; ++sweep) {
        float off = fabsf(S[1]) + fabsf(S[2]) + fabsf(S[5]);
        float base = fabsf(S[0]) + fabsf(S[4]) + fabsf(S[8]);
        if (off <= 1e-7f * base) break;
        for (int pi = 0; pi < 3; ++pi) {
            const int p = (pi == 2) ? 1 : 0;
            const int q = (pi == 0) ? 1 : 2;
            float apq = S[p*3+q];
            if (apq == 0.f) continue;
            float app = S[p*3+p], aqq = S[q*3+q];
            float tau = (aqq - app) / (2.f * apq);
            float tt  = ((tau >= 0.f) ? 1.f : -1.f) / (fabsf(tau) + sqrtf(1.f + tau*tau));
            float c = 1.f / sqrtf(1.f + tt*tt);
            float s = tt * c;
            for (int k = 0; k < 3; ++k) {
                float skp = S[k*3+p], skq = S[k*3+q];
                S[k*3+p] = c*skp - s*skq;
                S[k*3+q] = s*skp + c*skq;
            }
            for (int k = 0; k < 3; ++k) {
                float spk = S[p*3+k], sqk = S[q*3+k];
                S[p*3+k] = c*spk - s*sqk;
                S[q*3+k] = s*spk + c*sqk;
            }
            for (int k = 0; k < 3; ++k) {
                float vkp = Vm[k*3+p], vkq = Vm[k*3+q];
                Vm[k*3+p] = c*vkp - s*vkq;
                Vm[k*3+q] = s*vkp + c*vkq;
            }
        }
    }
    float lam[3] = {S[0], S[4], S[8]};
    int ord[3] = {0, 1, 2};
    for (int i = 0; i < 2; ++i)
        for (int j = i+1; j < 3; ++j)
            if (lam[ord[j]] > lam[ord[i]]) { int tmp = ord[i]; ord[i] = ord[j]; ord[j] = tmp; }
    for (int i = 0; i < 3; ++i) {
        int o = ord[i];
        float l = lam[o] > 0.f ? lam[o] : 0.f;
        sig[i] = sqrtf(l);
        for (int k = 0; k < 3; ++k) V[k*3+i] = Vm[k*3+o];
    }
    for (int i = 0; i < 3; ++i) {
        float u0 = 0, u1 = 0, u2 = 0;
        for (int k = 0; k < 3; ++k) {
            u0 += A[0*3+k] * V[k*3+i];
            u1 += A[1*3+k] * V[k*3+i];
            u2 += A[2*3+k] * V[k*3+i];
        }
        float nrm = sqrtf(u0*u0 + u1*u1 + u2*u2);
        if (nrm > 1e-30f) { u0 /= nrm; u1 /= nrm; u2 /= nrm; }
        else {
            float ax = U[0], ay = U[3], az = U[6];
            float bx = U[1], by = U[4], bz = U[7];
            u0 = ay*bz - az*by; u1 = az*bx - ax*bz; u2 = ax*by - ay*bx;
        }
        U[0*3+i] = u0; U[1*3+i] = u1; U[2*3+i] = u2;
    }
}

// u,s,vT = svd(H); v=vT^T; d=det(v@u^T); v[2,2]*=d; R = v' @ u^T;
// t[j] = p2c[j] - sum_k p1c[k]*R[k][j]
__device__ void compute_Rt(const float* H, const float* p1c, const float* p2c,
                           float* Rout, float* tout) {
    float U[9], V[9], sig[3];
    svd3x3f(H, U, V, sig);
    float d = (det3f(U) * det3f(V) < 0.f) ? -1.f : 1.f;
    V[2*3+2] *= d;
    float R[9];
    for (int i = 0; i < 3; ++i)
        for (int j = 0; j < 3; ++j) {
            float s = 0.f;
            for (int k = 0; k < 3; ++k) s += V[i*3+k] * U[j*3+k];
            R[i*3+j] = s;
        }
    for (int j = 0; j < 3; ++j) {
        float s = 0.f;
        for (int k = 0; k < 3; ++k) s += p1c[k] * R[k*3+j];
        tout[j] = p2c[j] - s;
    }
    for (int k = 0; k < 9; ++k) Rout[k] = R[k];
}

__device__ inline float wred(float v) {
    v += __shfl_down(v, 32);
    v += __shfl_down(v, 16);
    v += __shfl_down(v, 8);
    v += __shfl_down(v, 4);
    v += __shfl_down(v, 2);
    v += __shfl_down(v, 1);
    return v;   // valid on lane 0 of each wave
}

// Per-batch rigid-transform estimation. src1 = "q1" cloud, src2 = "q2" cloud;
// matched[i] = src2[gather(i)] (gather from batch-3 nn row, or identity).
template<bool C1, bool C2, bool G>
__device__ void batch_transform(const float* __restrict__ src1,
                                const float* __restrict__ src2,
                                const unsigned long long* __restrict__ nn_row,
                                int b, int t,
                                float lred[4][9], float* sc1, float* sc2,
                                float* sR, float* sT) {
    const int wave = t >> 6, lane = t & 63;
    float v6[6] = {0,0,0,0,0,0};
    for (int i = t; i < N; i += 256) {
        const float* tp = &src1[(b*N + i)*3];
        v6[0] += ldf<C1>(tp); v6[1] += ldf<C1>(tp+1); v6[2] += ldf<C1>(tp+2);
        const int mi = G ? (int)(unsigned int)(cohld64(&nn_row[i]) & 0xffffffffULL) : i;
        const float* mp = &src2[(b*N + mi)*3];
        v6[3] += ldf<C2>(mp); v6[4] += ldf<C2>(mp+1); v6[5] += ldf<C2>(mp+2);
    }
    #pragma unroll
    for (int k = 0; k < 6; ++k) v6[k] = wred(v6[k]);
    if (lane == 0) {
        #pragma unroll
        for (int k = 0; k < 6; ++k) lred[wave][k] = v6[k];
    }
    __syncthreads();
    if (t == 0) {
        #pragma unroll
        for (int k = 0; k < 3; ++k) {
            sc1[k] = (lred[0][k]  +lred[1][k]  +lred[2][k]  +lred[3][k])   / (float)N;
            sc2[k] = (lred[0][3+k]+lred[1][3+k]+lred[2][3+k]+lred[3][3+k]) / (float)N;
        }
    }
    __syncthreads();
    const float c1x = sc1[0], c1y = sc1[1], c1z = sc1[2];
    const float c2x = sc2[0], c2y = sc2[1], c2z = sc2[2];

    float h[9];
    #pragma unroll
    for (int k = 0; k < 9; ++k) h[k] = 0.f;
    for (int i = t; i < N; i += 256) {
        const float* tp = &src1[(b*N + i)*3];
        const float x1 = ldf<C1>(tp), y1 = ldf<C1>(tp+1), z1 = ldf<C1>(tp+2);
        const int mi = G ? (int)(unsigned int)(cohld64(&nn_row[i]) & 0xffffffffULL) : i;
        const float* mp = &src2[(b*N + mi)*3];
        const float x2 = ldf<C2>(mp), y2 = ldf<C2>(mp+1), z2 = ldf<C2>(mp+2);
        const float bx = x1-c1x, by = y1-c1y, bz = z1-c1z; // q1
        const float ax = x2-c2x, ay = y2-c2y, az = z2-c2z; // q2
        h[0] += ax*bx; h[1] += ax*by; h[2] += ax*bz;
        h[3] += ay*bx; h[4] += ay*by; h[5] += ay*bz;
        h[6] += az*bx; h[7] += az*by; h[8] += az*bz;
    }
    #pragma unroll
    for (int k = 0; k < 9; ++k) h[k] = wred(h[k]);
    if (lane == 0) {
        #pragma unroll
        for (int k = 0; k < 9; ++k) lred[wave][k] = h[k];
    }
    __syncthreads();
    if (t == 0) {
        float H[9], c1d[3], c2d[3];
        for (int k = 0; k < 9; ++k)
            H[k] = lred[0][k]+lred[1][k]+lred[2][k]+lred[3][k];
        c1d[0] = c1x; c1d[1] = c1y; c1d[2] = c1z;
        c2d[0] = c2x; c2d[1] = c2y; c2d[2] = c2z;
        compute_Rt(H, c1d, c2d, sR, sT);
    }
    __syncthreads();
}

// ---------------- the single kernel ----------------
__global__ void __launch_bounds__(256) k_icp(const float* __restrict__ p1,
                                             const float* __restrict__ p2,
                                             float* __restrict__ out,
                                             float* __restrict__ temp,
                                             unsigned long long* __restrict__ nn0,
                                             unsigned long long* __restrict__ nn1,
                                             unsigned* __restrict__ bar_cnt,
                                             int* __restrict__ done_flag) {
    const int t   = threadIdx.x;
    const int blk = blockIdx.x;
    unsigned baridx = 0;

    __shared__ float4 sc4[CC];
    __shared__ float lred[4][9];
    __shared__ float sc1[3], sc2[3], sR[9], sT[3];
    __shared__ float lds4[4];
    __shared__ int sdone;

    // block roles for NN phase
    const int nc  = blk & 15;          // candidate chunk  (16 x 128)
    const int nqc = (blk >> 4) & 1;    // query chunk      (2 x 1024)
    const int nb  = blk >> 5;          // batch            (4)
    const int cb  = nc * CC;
    const int qb  = nqc * 1024;

    float prev_err = 0.f;   // live only in block 4, thread 0

    // ---- init: temp = p1 (coh), nn0 = empty (coh) ----
    for (int i = blk*256 + t; i < B*N*3; i += NBLK*256) cohstf(&temp[i], p1[i]);
    for (int i = blk*256 + t; i < B*N;   i += NBLK*256) cohst64(&nn0[i], ~0ULL);
    gridbar(bar_cnt, ++baridx);

    for (int it = 0; it < MAXIT; ++it) {
        if (t == 0)
            sdone = __hip_atomic_load(done_flag, __ATOMIC_RELAXED, __HIP_MEMORY_SCOPE_AGENT);
        __syncthreads();
        if (sdone) break;

        unsigned long long* nn_cur  = (it & 1) ? nn1 : nn0;
        unsigned long long* nn_next = (it & 1) ? nn0 : nn1;

        // ---- NN phase: all 128 blocks; 4 queries/thread, CC cands in LDS ----
        {
            if (t < CC) {
                const float* src = &temp[(nb*N + cb + t)*3];
                sc4[t] = make_float4(cohldf(src), cohldf(src+1), cohldf(src+2), 0.f);
            }
            __syncthreads();
            // 4 consecutive queries per thread: 12 floats = 3 float4 loads
            const float4* p2v = (const float4*)(p2 + (size_t)(nb*N + qb)*3);
            const float4 A = p2v[t*3+0], Bv = p2v[t*3+1], Cv = p2v[t*3+2];
            const float px[NQ] = {A.x, A.w, Bv.z, Cv.y};
            const float py[NQ] = {A.y, Bv.x, Bv.w, Cv.z};
            const float pz[NQ] = {A.z, Bv.y, Cv.x, Cv.w};
            float bestd[NQ];
            int   besti[NQ];
            #pragma unroll
            for (int k = 0; k < NQ; ++k) { bestd[k] = __uint_as_float(0x7f7fffffu); besti[k] = 0; }
            #pragma unroll 4
            for (int j = 0; j < CC; ++j) {
                const float4 c = sc4[j];
                #pragma unroll
                for (int k = 0; k < NQ; ++k) {
                    const float dx = px[k] - c.x;
                    const float dy = py[k] - c.y;
                    const float dz = pz[k] - c.z;
                    const float d2 = dx*dx + dy*dy + dz*dz;
                    if (d2 < bestd[k]) { bestd[k] = d2; besti[k] = cb + j; }
                }
            }
            #pragma unroll
            for (int k = 0; k < NQ; ++k) {
                const int q = qb + t*NQ + k;
                unsigned long long pack =
                    ((unsigned long long)__float_as_uint(bestd[k]) << 32) | (unsigned int)besti[k];
                atomicMin(&nn_cur[nb*N + q], pack);
            }
        }
        gridbar(bar_cnt, ++baridx);

        // ---- reduce phase: blocks 0..3 per-batch, block 4 mean-err ----
        if (blk == 4) {
            float s = 0.f;
            for (int i = t; i < B*N; i += 256) {
                unsigned long long v = cohld64(&nn_cur[i]);
                s += sqrtf(__uint_as_float((unsigned int)(v >> 32)));
                cohst64(&nn_next[i], ~0ULL);
            }
            s = wred(s);
            if ((t & 63) == 0) lds4[t >> 6] = s;
            __syncthreads();
            if (t == 0) {
                float tot = lds4[0] + lds4[1] + lds4[2] + lds4[3];
                float meanerr = tot / (float)(B*N);
                __hip_atomic_store(done_flag,
                                   (fabsf(prev_err - meanerr) < TOL) ? 1 : 0,
                                   __ATOMIC_RELAXED, __HIP_MEMORY_SCOPE_AGENT);
                prev_err = meanerr;
            }
        } else if (blk < 4) {
            const int b = blk;
            batch_transform<true, false, true>(temp, p2, &nn_cur[3*N], b, t,
                                               lred, sc1, sc2, sR, sT);
            // temp[b] = temp[b] @ R + t   (coh read+write)
            for (int i = t; i < N; i += 256) {
                float* tp = &temp[(b*N + i)*3];
                const float x = cohldf(tp), y = cohldf(tp+1), z = cohldf(tp+2);
                cohstf(tp,   x*sR[0] + y*sR[3] + z*sR[6] + sT[0]);
                cohstf(tp+1, x*sR[1] + y*sR[4] + z*sR[7] + sT[1]);
                cohstf(tp+2, x*sR[2] + y*sR[5] + z*sR[8] + sT[2]);
            }
        }
        gridbar(bar_cnt, ++baridx);
    }

    // ---- final: T = get_transform(p1, temp) ----
    if (blk < 4) {
        const int b = blk;
        batch_transform<false, true, false>(p1, temp, nullptr, b, t,
                                            lred, sc1, sc2, sR, sT);
        if (t == 0) {
            for (int i = 0; i < 3; ++i) {
                out[b*12 + i*4 + 0] = sR[i*3+0];
                out[b*12 + i*4 + 1] = sR[i*3+1];
                out[b*12 + i*4 + 2] = sR[i*3+2];
                out[b*12 + i*4 + 3] = sT[i];
            }
        }
    }
}

extern "C" void kernel_launch(void* const* d_in, const int* in_sizes, int n_in,
                              void* d_out, int out_size, void* d_ws, size_t ws_size,
                              hipStream_t stream) {
    const float* p1 = (const float*)d_in[0];
    const float* p2 = (const float*)d_in[1];
    float* out  = (float*)d_out;
    float* temp = (float*)d_ws;
    unsigned long long* nn0 = (unsigned long long*)((char*)d_ws + 98304);
    unsigned long long* nn1 = (unsigned long long*)((char*)d_ws + 163840);
    unsigned* bar_cnt = (unsigned*)((char*)d_ws + 229376);
    int* done = (int*)((char*)d_ws + 229632);

    // zero barrier counter + done flag (poisoned 0xAA before every launch)
    hipMemsetAsync((char*)d_ws + 229376, 0, 512, stream);

    void* args[] = { (void*)&p1, (void*)&p2, (void*)&out, (void*)&temp,
                     (void*)&nn0, (void*)&nn1, (void*)&bar_cnt, (void*)&done };
    hipLaunchCooperativeKernel((const void*)k_icp, dim3(NBLK), dim3(256),
                               args, 0, stream);
}